// Round 4
// baseline (1622.698 us; speedup 1.0000x reference)
//
#include <hip/hip_runtime.h>

// Point2Voxel: scatter-mean of point features into a B x 64^3 voxel grid.
// Outputs (flat, in order): masked_pc[N*3], voxel_feats[B*V*32],
// voxel_counts[B*V], inst_flag[B]  -- all float32.
//
// Binning matches XLA's compiled arithmetic: XLA canonicalizes
// `t / 0.05` into `t * float32(1/0.05)` == `t * 20.0f`. Evidence trail:
//  R1/R2 (IEEE f32 divide)  -> absmax 2.359375 (tens of mis-binned points)
//  R3   (IEEE f64 divide)   -> absmax 2.796875 (different tens)
// -> ref is a third, f32-family semantics = reciprocal multiply.
// contract(off) is LOAD-BEARING: fusing (x+HALF)*20 into an FMA would
// change rounding and re-introduce mis-binning.

static constexpr int kNX  = 64;
static constexpr int kNYZ = 64 * 64;
static constexpr int kV   = 64 * 64 * 64;
static constexpr int kB   = 8;
static constexpr int kC   = 32;

__global__ void __launch_bounds__(256) p2v_main(
    const float* __restrict__ pc, const float* __restrict__ feat,
    const int* __restrict__ bid, float* __restrict__ masked_pc,
    float* __restrict__ voxel_feats, float* __restrict__ voxel_counts,
    float* __restrict__ inst_flag, int n)
{
#pragma clang fp contract(off) reassociate(off)
  int i = blockIdx.x * blockDim.x + threadIdx.x;
  if (i >= n) return;

  // HALF = float(0.5*64*0.05) = 1.60000002384f; INV_UNIT = f32(1/0.05) = 20.0f
  const float HALF     = (float)(0.5 * 64 * 0.05);
  const float INV_UNIT = 20.0f;

  float x = pc[3 * i + 0];
  float y = pc[3 * i + 1];
  float z = pc[3 * i + 2];

  bool valid = (fabsf(x) <= HALF) && (fabsf(y) <= HALF) && (fabsf(z) <= HALF);

  masked_pc[3 * i + 0] = valid ? x : 0.0f;
  masked_pc[3 * i + 1] = valid ? y : 0.0f;
  masked_pc[3 * i + 2] = valid ? z : 0.0f;

  if (!valid) return;

  // XLA semantics: f32 add, f32 multiply by 20.0f (separate roundings —
  // no FMA contraction), truncate toward zero, clip.
  float tx = x + HALF;
  float ty = y + HALF;
  float tz = z + HALF;
  int ix = (int)(tx * INV_UNIT);
  int iy = (int)(ty * INV_UNIT);
  int iz = (int)(tz * INV_UNIT);
  ix = min(max(ix, 0), kNX - 1);
  iy = min(max(iy, 0), kNX - 1);
  iz = min(max(iz, 0), kNX - 1);

  int b = bid[i];
  size_t lin = (size_t)b * kV + (size_t)(ix * kNYZ + iy * kNX + iz);

  atomicAdd(voxel_counts + lin, 1.0f);
  inst_flag[b] = 1.0f;  // benign race: every writer stores the same 1.0f

  float*       dst = voxel_feats + lin * kC;
  const float* src = feat + (size_t)i * kC;
#pragma unroll
  for (int c = 0; c < kC; ++c) {
    atomicAdd(dst + c, src[c]);
  }
}

__global__ void __launch_bounds__(256) p2v_finalize(
    float* __restrict__ voxel_feats, const float* __restrict__ voxel_counts)
{
#pragma clang fp contract(off) reassociate(off)
  int v = blockIdx.x * blockDim.x + threadIdx.x;
  if (v >= kB * kV) return;
  float c = voxel_counts[v];
  // count==0: feats already 0 (0/1=0). count==1: divide by 1 is a no-op.
  if (c >= 2.0f) {
    float* p = voxel_feats + (size_t)v * kC;
#pragma unroll
    for (int k = 0; k < kC; ++k) {
      p[k] = (float)((double)p[k] / (double)c);  // IEEE f32 quotient
    }
  }
}

extern "C" void kernel_launch(void* const* d_in, const int* in_sizes, int n_in,
                              void* d_out, int out_size, void* d_ws, size_t ws_size,
                              hipStream_t stream) {
  const float* pc   = (const float*)d_in[0];
  const float* feat = (const float*)d_in[1];
  const int*   bid  = (const int*)d_in[2];
  float* out = (float*)d_out;

  int n = in_sizes[0] / 3;

  float* masked_pc    = out;
  float* voxel_feats  = out + (size_t)3 * n;
  float* voxel_counts = voxel_feats + (size_t)kB * kV * kC;
  float* inst_flag    = voxel_counts + (size_t)kB * kV;

  // Zero everything after masked_pc (feats + counts + flags): d_out is
  // poisoned 0xAA before every timed launch, and empty voxels must be 0.
  size_t tail_floats = (size_t)kB * kV * kC + (size_t)kB * kV + kB;
  hipMemsetAsync(voxel_feats, 0, tail_floats * sizeof(float), stream);

  const int block = 256;
  p2v_main<<<(n + block - 1) / block, block, 0, stream>>>(
      pc, feat, bid, masked_pc, voxel_feats, voxel_counts, inst_flag, n);

  int nv = kB * kV;
  p2v_finalize<<<(nv + block - 1) / block, block, 0, stream>>>(
      voxel_feats, voxel_counts);
}

// Round 5
// 533.314 us; speedup vs baseline: 3.0427x; 3.0427x over previous
//
#include <hip/hip_runtime.h>

// Point2Voxel: scatter-mean of point features into a B x 64^3 voxel grid.
// Outputs (flat, in order): masked_pc[N*3], voxel_feats[B*V*32],
// voxel_counts[B*V], inst_flag[B]  -- all float32.
//
// Binning matches XLA's compiled arithmetic: `t / 0.05` is canonicalized to
// `t * 20.0f` (single f32 round each op, NO FMA). contract(off) is
// LOAD-BEARING. Evidence: R2 (f32 div) absmax 2.36, R3 (f64 div) 2.80,
// R4 (f32 mul, no fma) PASS at 0.0039.
//
// R4 counters: feat atomics with lane=point scattered 64 lines/instruction
// -> 1275us, 0.1% VALU, 8% HBM (atomic serialization). R5: transpose the
// scatter (lane=channel) so each wave's atomics cover 2 contiguous 128B
// regions -> per-line coalesced L2 atomics, 16x fewer transactions.

static constexpr int kNX  = 64;
static constexpr int kNYZ = 64 * 64;
static constexpr int kV   = 64 * 64 * 64;
static constexpr int kB   = 8;
static constexpr int kC   = 32;

// Kernel A: per-point bookkeeping. Writes masked_pc, voxel linear index
// (or -1) into ws, count atomics, inst_flag.
__global__ void __launch_bounds__(256) p2v_index(
    const float* __restrict__ pc, const int* __restrict__ bid,
    float* __restrict__ masked_pc, int* __restrict__ lin_out,
    float* __restrict__ voxel_counts, float* __restrict__ inst_flag, int n)
{
#pragma clang fp contract(off) reassociate(off)
  int i = blockIdx.x * blockDim.x + threadIdx.x;
  if (i >= n) return;

  // HALF = float(0.5*64*0.05) = 1.60000002384f; XLA: divide -> * 20.0f
  const float HALF     = (float)(0.5 * 64 * 0.05);
  const float INV_UNIT = 20.0f;

  float x = pc[3 * i + 0];
  float y = pc[3 * i + 1];
  float z = pc[3 * i + 2];

  bool valid = (fabsf(x) <= HALF) && (fabsf(y) <= HALF) && (fabsf(z) <= HALF);

  masked_pc[3 * i + 0] = valid ? x : 0.0f;
  masked_pc[3 * i + 1] = valid ? y : 0.0f;
  masked_pc[3 * i + 2] = valid ? z : 0.0f;

  if (!valid) {
    lin_out[i] = -1;
    return;
  }

  // XLA semantics: f32 add, f32 mul by 20.0f (separate roundings), trunc, clip.
  float tx = x + HALF;
  float ty = y + HALF;
  float tz = z + HALF;
  int ix = (int)(tx * INV_UNIT);
  int iy = (int)(ty * INV_UNIT);
  int iz = (int)(tz * INV_UNIT);
  ix = min(max(ix, 0), kNX - 1);
  iy = min(max(iy, 0), kNX - 1);
  iz = min(max(iz, 0), kNX - 1);

  int b = bid[i];
  int lin = b * kV + ix * kNYZ + iy * kNX + iz;
  lin_out[i] = lin;

  atomicAdd(voxel_counts + lin, 1.0f);
  inst_flag[b] = 1.0f;  // benign race: every writer stores the same 1.0f
}

// Kernel B: transposed feature scatter. gid = point*32 + channel, so one
// wave's 64 lanes cover 2 points x 32 contiguous channels = 2 cache-line
// pairs -> the TA coalesces same-line distinct-dword atomics per line.
__global__ void __launch_bounds__(256) p2v_scatter(
    const float* __restrict__ feat, const int* __restrict__ lin_in,
    float* __restrict__ voxel_feats, int n)
{
  int gid = blockIdx.x * blockDim.x + threadIdx.x;
  if (gid >= n * kC) return;
  int i = gid >> 5;        // point
  int c = gid & (kC - 1);  // channel
  int lin = lin_in[i];
  if (lin < 0) return;
  atomicAdd(voxel_feats + (size_t)lin * kC + c, feat[(size_t)i * kC + c]);
}

__global__ void __launch_bounds__(256) p2v_finalize(
    float* __restrict__ voxel_feats, const float* __restrict__ voxel_counts)
{
#pragma clang fp contract(off) reassociate(off)
  int v = blockIdx.x * blockDim.x + threadIdx.x;
  if (v >= kB * kV) return;
  float c = voxel_counts[v];
  // count==0: feats already 0 (0/1=0). count==1: divide by 1 is a no-op.
  if (c >= 2.0f) {
    float* p = voxel_feats + (size_t)v * kC;
#pragma unroll
    for (int k = 0; k < kC; ++k) {
      p[k] = (float)((double)p[k] / (double)c);  // IEEE f32 quotient
    }
  }
}

extern "C" void kernel_launch(void* const* d_in, const int* in_sizes, int n_in,
                              void* d_out, int out_size, void* d_ws, size_t ws_size,
                              hipStream_t stream) {
  const float* pc   = (const float*)d_in[0];
  const float* feat = (const float*)d_in[1];
  const int*   bid  = (const int*)d_in[2];
  float* out = (float*)d_out;

  int n = in_sizes[0] / 3;

  float* masked_pc    = out;
  float* voxel_feats  = out + (size_t)3 * n;
  float* voxel_counts = voxel_feats + (size_t)kB * kV * kC;
  float* inst_flag    = voxel_counts + (size_t)kB * kV;

  int* lin_ws = (int*)d_ws;  // n ints = 4 MB scratch

  // Zero everything after masked_pc (feats + counts + flags): d_out is
  // poisoned 0xAA before every timed launch, and empty voxels must be 0.
  size_t tail_floats = (size_t)kB * kV * kC + (size_t)kB * kV + kB;
  hipMemsetAsync(voxel_feats, 0, tail_floats * sizeof(float), stream);

  const int block = 256;
  p2v_index<<<(n + block - 1) / block, block, 0, stream>>>(
      pc, bid, masked_pc, lin_ws, voxel_counts, inst_flag, n);

  long long nb = (long long)n * kC;
  p2v_scatter<<<(int)((nb + block - 1) / block), block, 0, stream>>>(
      feat, lin_ws, voxel_feats, n);

  int nv = kB * kV;
  p2v_finalize<<<(nv + block - 1) / block, block, 0, stream>>>(
      voxel_feats, voxel_counts);
}

// Round 6
// 465.698 us; speedup vs baseline: 3.4844x; 1.1452x over previous
//
#include <hip/hip_runtime.h>

// Point2Voxel: scatter-mean of point features into a B x 64^3 voxel grid.
// Outputs (flat, in order): masked_pc[N*3], voxel_feats[B*V*32],
// voxel_counts[B*V], inst_flag[B]  -- all float32.
//
// Binning matches XLA's compiled arithmetic: `t / 0.05` canonicalized to
// `t * 20.0f` (separate f32 roundings, NO FMA -> contract(off) LOAD-BEARING).
// Evidence: R2 (f32 div) 2.36, R3 (f64 div) 2.80, R4 (mul) PASS 0.0039.
//
// R6 scheme: gather, not scatter. Per-voxel linked lists (atomicExch push)
// built in ws; one gather kernel writes every feats/counts byte EXACTLY once
// (no 277 MB memset, no atomic RMW on the 268 MB feats region, no finalize
// RMW). Ideal traffic ~430 MB -> ~70 us @ 6.3 TB/s.

static constexpr int kNX  = 64;
static constexpr int kNYZ = 64 * 64;
static constexpr int kV   = 64 * 64 * 64;
static constexpr int kB   = 8;
static constexpr int kC   = 32;

// ---------------- fast path: linked-list gather ----------------

// Kernel A: per-point. masked_pc, validity, list push, inst_flag.
__global__ void __launch_bounds__(256) p2v_build(
    const float* __restrict__ pc, const int* __restrict__ bid,
    float* __restrict__ masked_pc, int* __restrict__ head,
    int* __restrict__ nxt, float* __restrict__ inst_flag, int n)
{
#pragma clang fp contract(off) reassociate(off)
  int i = blockIdx.x * blockDim.x + threadIdx.x;
  if (i >= n) return;

  const float HALF     = (float)(0.5 * 64 * 0.05);  // 1.60000002384f
  const float INV_UNIT = 20.0f;                      // XLA: /0.05 -> *20.0f

  float x = pc[3 * i + 0];
  float y = pc[3 * i + 1];
  float z = pc[3 * i + 2];

  bool valid = (fabsf(x) <= HALF) && (fabsf(y) <= HALF) && (fabsf(z) <= HALF);

  masked_pc[3 * i + 0] = valid ? x : 0.0f;
  masked_pc[3 * i + 1] = valid ? y : 0.0f;
  masked_pc[3 * i + 2] = valid ? z : 0.0f;

  if (!valid) return;

  float tx = x + HALF;
  float ty = y + HALF;
  float tz = z + HALF;
  int ix = (int)(tx * INV_UNIT);
  int iy = (int)(ty * INV_UNIT);
  int iz = (int)(tz * INV_UNIT);
  ix = min(max(ix, 0), kNX - 1);
  iy = min(max(iy, 0), kNX - 1);
  iz = min(max(iz, 0), kNX - 1);

  int lin = bid[i] * kV + ix * kNYZ + iy * kNX + iz;

  nxt[i] = atomicExch(head + lin, i);  // lock-free stack push
  inst_flag[bid[i]] = 1.0f;            // benign race: same value
}

// Kernel B: gather. 8 lanes per voxel, each lane owns 4 channels (float4).
// A wave covers 8 voxels: head reads broadcast per voxel-group, feat reads
// and feats/counts writes fully coalesced.
__global__ void __launch_bounds__(256) p2v_gather(
    const float* __restrict__ feat, const int* __restrict__ head,
    const int* __restrict__ nxt, float* __restrict__ voxel_feats,
    float* __restrict__ voxel_counts)
{
#pragma clang fp contract(off) reassociate(off)
  int gid = blockIdx.x * blockDim.x + threadIdx.x;  // < B*V*8
  int v  = gid >> 3;
  int c4 = (gid & 7) * 4;
  if (v >= kB * kV) return;

  float4 sum = make_float4(0.f, 0.f, 0.f, 0.f);
  int cnt = 0;
  int h = head[v];
  while (h >= 0) {
    const float4 f = *(const float4*)(feat + (size_t)h * kC + c4);
    sum.x += f.x; sum.y += f.y; sum.z += f.z; sum.w += f.w;
    ++cnt;
    h = nxt[h];
  }

  if (cnt >= 2) {
    double dc = (double)cnt;  // IEEE f32-equivalent quotient via double
    sum.x = (float)((double)sum.x / dc);
    sum.y = (float)((double)sum.y / dc);
    sum.z = (float)((double)sum.z / dc);
    sum.w = (float)((double)sum.w / dc);
  }
  *(float4*)(voxel_feats + (size_t)v * kC + c4) = sum;

  if (c4 == 0) voxel_counts[v] = (float)cnt;
}

// ---------------- fallback path (ws too small): R4/R5 atomic scheme --------

__global__ void __launch_bounds__(256) p2v_main_fb(
    const float* __restrict__ pc, const float* __restrict__ feat,
    const int* __restrict__ bid, float* __restrict__ masked_pc,
    float* __restrict__ voxel_feats, float* __restrict__ voxel_counts,
    float* __restrict__ inst_flag, int n)
{
#pragma clang fp contract(off) reassociate(off)
  int i = blockIdx.x * blockDim.x + threadIdx.x;
  if (i >= n) return;
  const float HALF = (float)(0.5 * 64 * 0.05);
  const float INV_UNIT = 20.0f;
  float x = pc[3 * i + 0], y = pc[3 * i + 1], z = pc[3 * i + 2];
  bool valid = (fabsf(x) <= HALF) && (fabsf(y) <= HALF) && (fabsf(z) <= HALF);
  masked_pc[3 * i + 0] = valid ? x : 0.0f;
  masked_pc[3 * i + 1] = valid ? y : 0.0f;
  masked_pc[3 * i + 2] = valid ? z : 0.0f;
  if (!valid) return;
  int ix = (int)((x + HALF) * INV_UNIT);
  int iy = (int)((y + HALF) * INV_UNIT);
  int iz = (int)((z + HALF) * INV_UNIT);
  ix = min(max(ix, 0), kNX - 1);
  iy = min(max(iy, 0), kNX - 1);
  iz = min(max(iz, 0), kNX - 1);
  int b = bid[i];
  size_t lin = (size_t)b * kV + (size_t)(ix * kNYZ + iy * kNX + iz);
  atomicAdd(voxel_counts + lin, 1.0f);
  inst_flag[b] = 1.0f;
  float* dst = voxel_feats + lin * kC;
  const float* src = feat + (size_t)i * kC;
#pragma unroll
  for (int c = 0; c < kC; ++c) atomicAdd(dst + c, src[c]);
}

__global__ void __launch_bounds__(256) p2v_finalize_fb(
    float* __restrict__ voxel_feats, const float* __restrict__ voxel_counts)
{
#pragma clang fp contract(off) reassociate(off)
  int v = blockIdx.x * blockDim.x + threadIdx.x;
  if (v >= kB * kV) return;
  float c = voxel_counts[v];
  if (c >= 2.0f) {
    float* p = voxel_feats + (size_t)v * kC;
#pragma unroll
    for (int k = 0; k < kC; ++k) p[k] = (float)((double)p[k] / (double)c);
  }
}

// ---------------------------------------------------------------------------

extern "C" void kernel_launch(void* const* d_in, const int* in_sizes, int n_in,
                              void* d_out, int out_size, void* d_ws, size_t ws_size,
                              hipStream_t stream) {
  const float* pc   = (const float*)d_in[0];
  const float* feat = (const float*)d_in[1];
  const int*   bid  = (const int*)d_in[2];
  float* out = (float*)d_out;

  int n = in_sizes[0] / 3;

  float* masked_pc    = out;
  float* voxel_feats  = out + (size_t)3 * n;
  float* voxel_counts = voxel_feats + (size_t)kB * kV * kC;
  float* inst_flag    = voxel_counts + (size_t)kB * kV;

  const int block = 256;
  size_t need = (size_t)kB * kV * sizeof(int) + (size_t)n * sizeof(int);

  if (ws_size >= need) {
    // Fast path: linked-list gather.
    int* head = (int*)d_ws;            // B*V ints (8 MB)
    int* nxt  = head + (size_t)kB * kV;  // n ints (4 MB)

    // head := -1 (0xFF bytes); inst_flag := 0 (only outputs not written
    // unconditionally by a kernel).
    hipMemsetAsync(head, 0xFF, (size_t)kB * kV * sizeof(int), stream);
    hipMemsetAsync(inst_flag, 0, kB * sizeof(float), stream);

    p2v_build<<<(n + block - 1) / block, block, 0, stream>>>(
        pc, bid, masked_pc, head, nxt, inst_flag, n);

    long long ng = (long long)kB * kV * 8;  // 8 lanes per voxel
    p2v_gather<<<(int)((ng + block - 1) / block), block, 0, stream>>>(
        feat, head, nxt, voxel_feats, voxel_counts);
  } else {
    // Fallback: proven R5 atomic scheme (needs no ws).
    size_t tail_floats = (size_t)kB * kV * kC + (size_t)kB * kV + kB;
    hipMemsetAsync(voxel_feats, 0, tail_floats * sizeof(float), stream);
    p2v_main_fb<<<(n + block - 1) / block, block, 0, stream>>>(
        pc, feat, bid, masked_pc, voxel_feats, voxel_counts, inst_flag, n);
    int nv = kB * kV;
    p2v_finalize_fb<<<(nv + block - 1) / block, block, 0, stream>>>(
        voxel_feats, voxel_counts);
  }
}